// Round 2
// baseline (598.391 us; speedup 1.0000x reference)
//
#include <hip/hip_runtime.h>

typedef _Float16 f16;
typedef __attribute__((ext_vector_type(8))) _Float16 half8;
typedef __attribute__((ext_vector_type(2))) _Float16 half2v;
typedef __attribute__((ext_vector_type(4))) float float4v;

#define MODE_QK 0
#define MODE_V 1
#define MODE_PV 2
#define MODE_PROJ 3

// B=8 N=512 P=16 C=512 H=8 HD=64 E=1024
// ws layout (bytes):
//   0         : xf16 [B,N,P,C] f16 (67108864)   -> reused as yattn [B,H,N,E]
//   67108864  : vT   [B,H,E,N] f16 (67108864)   -> reused as ypre  [B,N,P,C]
//   134217728 : xmean[B,N,C]   f16 (4194304)
//   138412032 : WT   [1536,512]f16 (1572864)    (Wqkv transposed)
//   139984896 : WpT  [512,512] f16 (524288)
//   140509184 : q    [B,H,N,64]f16 (4194304)
//   144703488 : k    [B,H,N,64]f16 (4194304)
//   148897792 : P    [B,H,N,N] f16 (33554432)
// total 182452224 bytes

__global__ __launch_bounds__(256) void wt_kernel(const float* __restrict__ Wqkv,
    const float* __restrict__ Wproj, f16* __restrict__ WT, f16* __restrict__ WpT)
{
    int idx = blockIdx.x * 256 + threadIdx.x;          // 1048576 total
    if (idx < 1536 * 512) {
        int d = idx >> 9, c = idx & 511;
        WT[idx] = (f16)Wqkv[c * 1536 + d];
    } else {
        int i2 = idx - 1536 * 512;
        int d = i2 >> 9, c = i2 & 511;
        WpT[i2] = (f16)Wproj[c * 512 + d];
    }
}

__global__ __launch_bounds__(256) void xprep_kernel(const float* __restrict__ x,
    const float* __restrict__ mask, f16* __restrict__ xf, f16* __restrict__ xmean)
{
    int bn = blockIdx.x;           // 0..4095  (b*512+n)
    int t = threadIdx.x;           // 256
    const float* xrow = x + (size_t)bn * 16 * 512;
    const float* mrow = mask + (size_t)bn * 16;
    float msum = 0.f;
    #pragma unroll
    for (int p = 0; p < 16; p++) msum += mrow[p];
    int c = t * 2;
    float a0 = 0.f, a1 = 0.f;
    #pragma unroll
    for (int p = 0; p < 16; p++) {
        float2 v = *(const float2*)(xrow + p * 512 + c);
        float m = mrow[p];
        a0 += m * v.x; a1 += m * v.y;
        half2v h; h[0] = (f16)v.x; h[1] = (f16)v.y;
        *(half2v*)(xf + (size_t)bn * 16 * 512 + p * 512 + c) = h;
    }
    float inv = 1.f / msum;
    half2v hm; hm[0] = (f16)(a0 * inv); hm[1] = (f16)(a1 * inv);
    *(half2v*)(xmean + (size_t)bn * 512 + c) = hm;
}

// Generic K=512 GEMM, 64x64 tile, BK=32, 256 threads (4 waves, each 32x32).
// A,B fragments: outer index = lane&15, k = (lane>>4)*8 + j (16x16x32 layout).
// C/D: col = lane&15, row = (lane>>4)*4 + reg.
template<int MODE>
__global__ __launch_bounds__(256) void gemm_k512(
    const f16* __restrict__ pA, const f16* __restrict__ pA2,
    const f16* __restrict__ pB,
    f16* __restrict__ outa, f16* __restrict__ outb,
    float* __restrict__ outf, const float* __restrict__ bias)
{
    __shared__ f16 As[64 * 40];    // row stride 40 f16 (80B) to spread banks
    __shared__ f16 Bs[64 * 40];
    const int t = threadIdx.x;
    const int lane = t & 63;
    const int w = t >> 6;
    const int wm = w & 1, wn = w >> 1;
    const int quad = lane >> 4, l15 = lane & 15;
    const int srow = t >> 2;
    const int koff = (t & 3) * 8;

    int m0 = blockIdx.x * 64;
    int n0 = blockIdx.y * 64;
    int vb = 0, vp = 0, z = 0;

    const f16* ag;
    const f16* bg;
    if constexpr (MODE == MODE_QK) {
        // A rows: j<512 -> x0 (p=0 slice of xf16, row stride 8192); else xmean
        ag = (n0 < 512) ? (pA + (size_t)(m0 + srow) * 8192 + koff)
                        : (pA2 + (size_t)(m0 + srow) * 512 + koff);
        bg = pB + (size_t)(n0 + srow) * 512 + koff;
    } else if constexpr (MODE == MODE_V) {
        z = blockIdx.z; vb = z >> 4; vp = z & 15;     // batch (b,p)
        ag = pA + (size_t)(m0 + srow) * 512 + koff;   // pA = WvT
        bg = pB + (((size_t)(vb * 512 + n0 + srow)) * 16 + vp) * 512 + koff;
    } else if constexpr (MODE == MODE_PV) {
        z = blockIdx.z;                               // bh
        ag = pA + ((size_t)z * 512 + m0 + srow) * 512 + koff;   // P rows
        bg = pB + ((size_t)z * 1024 + n0 + srow) * 512 + koff;  // vT rows
    } else {
        ag = pA + (size_t)(m0 + srow) * 512 + koff;   // ypre rows
        bg = pB + (size_t)(n0 + srow) * 512 + koff;   // WpT rows
    }

    float4v acc00 = {0.f,0.f,0.f,0.f}, acc01 = {0.f,0.f,0.f,0.f};
    float4v acc10 = {0.f,0.f,0.f,0.f}, acc11 = {0.f,0.f,0.f,0.f};

    for (int kt = 0; kt < 16; kt++) {
        half8 av = *(const half8*)ag; ag += 32;
        half8 bv = *(const half8*)bg; bg += 32;
        __syncthreads();
        *(half8*)&As[srow * 40 + koff] = av;
        *(half8*)&Bs[srow * 40 + koff] = bv;
        __syncthreads();
        half8 a0 = *(const half8*)&As[(wm * 32 + l15) * 40 + quad * 8];
        half8 a1 = *(const half8*)&As[(wm * 32 + 16 + l15) * 40 + quad * 8];
        half8 b0 = *(const half8*)&Bs[(wn * 32 + l15) * 40 + quad * 8];
        half8 b1 = *(const half8*)&Bs[(wn * 32 + 16 + l15) * 40 + quad * 8];
        acc00 = __builtin_amdgcn_mfma_f32_16x16x32_f16(a0, b0, acc00, 0, 0, 0);
        acc01 = __builtin_amdgcn_mfma_f32_16x16x32_f16(a0, b1, acc01, 0, 0, 0);
        acc10 = __builtin_amdgcn_mfma_f32_16x16x32_f16(a1, b0, acc10, 0, 0, 0);
        acc11 = __builtin_amdgcn_mfma_f32_16x16x32_f16(a1, b1, acc11, 0, 0, 0);
    }

    #pragma unroll
    for (int ms = 0; ms < 2; ms++) {
        #pragma unroll
        for (int ns = 0; ns < 2; ns++) {
            float4v a = ms == 0 ? (ns == 0 ? acc00 : acc01)
                                : (ns == 0 ? acc10 : acc11);
            #pragma unroll
            for (int i = 0; i < 4; i++) {
                int lrow = wm * 32 + ms * 16 + quad * 4 + i;
                int lcol = wn * 32 + ns * 16 + l15;
                float val = a[i];
                if constexpr (MODE == MODE_QK) {
                    int gm = m0 + lrow, gj = n0 + lcol;
                    int b = gm >> 9, n = gm & 511;
                    if (gj < 512)
                        outa[(((size_t)(b * 8 + (gj >> 6))) * 512 + n) * 64 + (gj & 63)] = (f16)val;
                    else {
                        int jj = gj - 512;
                        outb[(((size_t)(b * 8 + (jj >> 6))) * 512 + n) * 64 + (jj & 63)] = (f16)val;
                    }
                } else if constexpr (MODE == MODE_V) {
                    int gi = m0 + lrow, gn = n0 + lcol;
                    int h = gi >> 6, dd = gi & 63;
                    outa[(((size_t)(vb * 8 + h)) * 1024 + dd * 16 + vp) * 512 + gn] = (f16)val;
                } else if constexpr (MODE == MODE_PV) {
                    outa[((size_t)z * 512 + m0 + lrow) * 1024 + (n0 + lcol)] = (f16)val;
                } else {
                    outf[(size_t)(m0 + lrow) * 512 + (n0 + lcol)] = val + bias[n0 + lcol];
                }
            }
        }
    }
}

// Fused S = q k^T * 0.125 and row softmax, writes P (f16, normalized).
// grid (8 ntiles, 64 bh); block 256; wave w owns q-rows n0+16w..+16, all 512 cols.
__global__ __launch_bounds__(256) void qk_softmax_kernel(
    const f16* __restrict__ q, const f16* __restrict__ k, f16* __restrict__ Pout)
{
    __shared__ f16 qs[64 * 72];
    __shared__ f16 ks[512 * 72];
    const int t = threadIdx.x;
    const int bh = blockIdx.y;
    const int n0 = blockIdx.x * 64;
    // qs: 64 rows x 64 f16 = 512 half8 chunks; 256 threads -> 2 iters
    #pragma unroll
    for (int i = 0; i < 2; i++) {
        int cid = i * 256 + t;
        int row = cid >> 3, off = (cid & 7) * 8;
        *(half8*)&qs[row * 72 + off] =
            *(const half8*)&q[((size_t)bh * 512 + n0 + row) * 64 + off];
    }
    // ks: 512 rows x 64 f16 = 4096 half8 chunks; 256 threads -> 16 iters
    #pragma unroll
    for (int i = 0; i < 16; i++) {
        int cid = i * 256 + t;
        int row = cid >> 3, off = (cid & 7) * 8;
        *(half8*)&ks[row * 72 + off] =
            *(const half8*)&k[((size_t)bh * 512 + row) * 64 + off];
    }
    __syncthreads();
    const int lane = t & 63, w = t >> 6;
    const int quad = lane >> 4, l15 = lane & 15;
    const int qrow = w * 16 + l15;
    half8 a0 = *(const half8*)&qs[qrow * 72 + quad * 8];
    half8 a1 = *(const half8*)&qs[qrow * 72 + 32 + quad * 8];
    float4v acc[32];
    #pragma unroll
    for (int f = 0; f < 32; f++) {
        int krow = f * 16 + l15;
        half8 b0 = *(const half8*)&ks[krow * 72 + quad * 8];
        half8 b1 = *(const half8*)&ks[krow * 72 + 32 + quad * 8];
        float4v c = {0.f, 0.f, 0.f, 0.f};
        c = __builtin_amdgcn_mfma_f32_16x16x32_f16(a0, b0, c, 0, 0, 0);
        c = __builtin_amdgcn_mfma_f32_16x16x32_f16(a1, b1, c, 0, 0, 0);
        acc[f] = c;
    }
    float mx0 = -3e38f, mx1 = -3e38f, mx2 = -3e38f, mx3 = -3e38f;
    #pragma unroll
    for (int f = 0; f < 32; f++) {
        mx0 = fmaxf(mx0, acc[f][0]); mx1 = fmaxf(mx1, acc[f][1]);
        mx2 = fmaxf(mx2, acc[f][2]); mx3 = fmaxf(mx3, acc[f][3]);
    }
    #pragma unroll
    for (int off = 1; off < 16; off <<= 1) {
        mx0 = fmaxf(mx0, __shfl_xor(mx0, off));
        mx1 = fmaxf(mx1, __shfl_xor(mx1, off));
        mx2 = fmaxf(mx2, __shfl_xor(mx2, off));
        mx3 = fmaxf(mx3, __shfl_xor(mx3, off));
    }
    float s0 = 0.f, s1 = 0.f, s2 = 0.f, s3 = 0.f;
    #pragma unroll
    for (int f = 0; f < 32; f++) {
        float e0 = __expf(0.125f * (acc[f][0] - mx0));
        float e1 = __expf(0.125f * (acc[f][1] - mx1));
        float e2 = __expf(0.125f * (acc[f][2] - mx2));
        float e3 = __expf(0.125f * (acc[f][3] - mx3));
        acc[f][0] = e0; acc[f][1] = e1; acc[f][2] = e2; acc[f][3] = e3;
        s0 += e0; s1 += e1; s2 += e2; s3 += e3;
    }
    #pragma unroll
    for (int off = 1; off < 16; off <<= 1) {
        s0 += __shfl_xor(s0, off);
        s1 += __shfl_xor(s1, off);
        s2 += __shfl_xor(s2, off);
        s3 += __shfl_xor(s3, off);
    }
    float r0 = 1.f / s0, r1 = 1.f / s1, r2 = 1.f / s2, r3 = 1.f / s3;
    size_t base = ((size_t)bh * 512 + n0 + w * 16) * 512;
    #pragma unroll
    for (int f = 0; f < 32; f++) {
        int col = f * 16 + l15;
        Pout[base + (size_t)(quad * 4 + 0) * 512 + col] = (f16)(acc[f][0] * r0);
        Pout[base + (size_t)(quad * 4 + 1) * 512 + col] = (f16)(acc[f][1] * r1);
        Pout[base + (size_t)(quad * 4 + 2) * 512 + col] = (f16)(acc[f][2] * r2);
        Pout[base + (size_t)(quad * 4 + 3) * 512 + col] = (f16)(acc[f][3] * r3);
    }
}

// ypre[b,n,p, h*64+dd] = yattn[b,h,n, dd*16+p]
__global__ __launch_bounds__(256) void permute_kernel(
    const f16* __restrict__ ya, f16* __restrict__ yp)
{
    int idx = blockIdx.x;                 // (b*8+h)*512 + n
    int n = idx & 511, bh = idx >> 9;
    int h = bh & 7, b = bh >> 3;
    int t = threadIdx.x;
    int p = t >> 4, g = t & 15;
    const f16* src = ya + (size_t)idx * 1024;
    f16 v0 = src[(g * 4 + 0) * 16 + p];
    f16 v1 = src[(g * 4 + 1) * 16 + p];
    f16 v2 = src[(g * 4 + 2) * 16 + p];
    f16 v3 = src[(g * 4 + 3) * 16 + p];
    f16* dst = yp + ((size_t)(b * 512 + n) * 16 + p) * 512 + h * 64 + g * 4;
    dst[0] = v0; dst[1] = v1; dst[2] = v2; dst[3] = v3;
}

extern "C" void kernel_launch(void* const* d_in, const int* in_sizes, int n_in,
                              void* d_out, int out_size, void* d_ws, size_t ws_size,
                              hipStream_t stream)
{
    (void)in_sizes; (void)n_in; (void)out_size; (void)ws_size;
    const float* x     = (const float*)d_in[0];
    const float* mask  = (const float*)d_in[1];
    // d_in[2] lens, d_in[3] lens_mask: unused by the reference forward
    const float* Wqkv  = (const float*)d_in[4];
    const float* Wproj = (const float*)d_in[5];
    const float* bproj = (const float*)d_in[6];
    float* out = (float*)d_out;
    char* ws = (char*)d_ws;

    f16* xf16  = (f16*)(ws + 0);
    f16* vT    = (f16*)(ws + 67108864);
    f16* xmean = (f16*)(ws + 134217728);
    f16* WT    = (f16*)(ws + 138412032);
    f16* WpT   = (f16*)(ws + 139984896);
    f16* qb    = (f16*)(ws + 140509184);
    f16* kb    = (f16*)(ws + 144703488);
    f16* Pm    = (f16*)(ws + 148897792);
    f16* yattn = xf16;   // xf16 dead after V GEMM
    f16* ypre  = vT;     // vT dead after PV GEMM

    wt_kernel<<<dim3(4096), dim3(256), 0, stream>>>(Wqkv, Wproj, WT, WpT);
    xprep_kernel<<<dim3(4096), dim3(256), 0, stream>>>(x, mask, xf16, xmean);
    gemm_k512<MODE_QK><<<dim3(64, 16), dim3(256), 0, stream>>>(
        xf16, xmean, WT, qb, kb, nullptr, nullptr);
    gemm_k512<MODE_V><<<dim3(8, 8, 128), dim3(256), 0, stream>>>(
        WT + 1024 * 512, nullptr, xf16, vT, nullptr, nullptr, nullptr);
    qk_softmax_kernel<<<dim3(8, 64), dim3(256), 0, stream>>>(qb, kb, Pm);
    gemm_k512<MODE_PV><<<dim3(8, 16, 64), dim3(256), 0, stream>>>(
        Pm, nullptr, vT, yattn, nullptr, nullptr, nullptr);
    permute_kernel<<<dim3(32768), dim3(256), 0, stream>>>(yattn, ypre);
    gemm_k512<MODE_PROJ><<<dim3(1024, 8), dim3(256), 0, stream>>>(
        ypre, nullptr, WpT, nullptr, nullptr, out, bproj);
}

// Round 3
// 446.143 us; speedup vs baseline: 1.3413x; 1.3413x over previous
//
#include <hip/hip_runtime.h>

typedef _Float16 f16;
typedef __attribute__((ext_vector_type(8))) _Float16 half8;
typedef __attribute__((ext_vector_type(2))) _Float16 half2v;
typedef __attribute__((ext_vector_type(4))) float float4v;

#define MODE_QK 0
#define MODE_V 1
#define MODE_PV 2
#define MODE_PROJ 3

// B=8 N=512 P=16 C=512 H=8 HD=64 E=1024
// ws layout (bytes):
//   0         : xf16 [B,N,P,C] f16 (67108864)   -> reused as ypre [B,N,P,C]
//   67108864  : vT   [B,H,E',N] f16 (67108864)  (E' channel order = p*64+dd)
//   134217728 : xmean[B,N,C]   f16 (4194304)
//   138412032 : WT   [1536,512]f16 (1572864)    (Wqkv transposed)
//   139984896 : WpT  [512,512] f16 (524288)
//   140509184 : q    [B,H,N,64]f16 (4194304)
//   144703488 : k    [B,H,N,64]f16 (4194304)
//   148897792 : P    [B,H,N,N] f16 (33554432)
// total 182452224 bytes

__device__ __forceinline__ void gload16(const f16* g, f16* l) {
    __builtin_amdgcn_global_load_lds(
        (const __attribute__((address_space(1))) void*)g,
        (__attribute__((address_space(3))) void*)l, 16, 0, 0);
}

__global__ __launch_bounds__(256) void wt_kernel(const float* __restrict__ Wqkv,
    const float* __restrict__ Wproj, f16* __restrict__ WT, f16* __restrict__ WpT)
{
    int idx = blockIdx.x * 256 + threadIdx.x;          // 1048576 total
    if (idx < 1536 * 512) {
        int d = idx >> 9, c = idx & 511;
        WT[idx] = (f16)Wqkv[c * 1536 + d];
    } else {
        int i2 = idx - 1536 * 512;
        int d = i2 >> 9, c = i2 & 511;
        WpT[i2] = (f16)Wproj[c * 512 + d];
    }
}

__global__ __launch_bounds__(256) void xprep_kernel(const float* __restrict__ x,
    const float* __restrict__ mask, f16* __restrict__ xf, f16* __restrict__ xmean)
{
    int bn = blockIdx.x;           // 0..4095  (b*512+n)
    int t = threadIdx.x;           // 256
    const float* xrow = x + (size_t)bn * 16 * 512;
    const float* mrow = mask + (size_t)bn * 16;
    float msum = 0.f;
    #pragma unroll
    for (int p = 0; p < 16; p++) msum += mrow[p];
    int c = t * 2;
    float a0 = 0.f, a1 = 0.f;
    #pragma unroll
    for (int p = 0; p < 16; p++) {
        float2 v = *(const float2*)(xrow + p * 512 + c);
        float m = mrow[p];
        a0 += m * v.x; a1 += m * v.y;
        half2v h; h[0] = (f16)v.x; h[1] = (f16)v.y;
        *(half2v*)(xf + (size_t)bn * 16 * 512 + p * 512 + c) = h;
    }
    float inv = 1.f / msum;
    half2v hm; hm[0] = (f16)(a0 * inv); hm[1] = (f16)(a1 * inv);
    *(half2v*)(xmean + (size_t)bn * 512 + c) = hm;
}

// 128x128 tile, K=512, BK=32, 256 threads = 4 waves in 2x2; each wave 64x64
// (4x4 fragments of 16x16x32). A,B staged via global_load_lds width=16.
// LDS tiles row-major [128][32] f16 (no padding: global_load_lds needs
// lane-contiguous destinations).
// MFMA A/B frag: row = lane&15, k = (lane>>4)*8 + j.
// C/D: col = lane&15, row = (lane>>4)*4 + reg.
template<int MODE>
__global__ __launch_bounds__(256) void gemm128(
    const f16* __restrict__ pA, const f16* __restrict__ pA2,
    const f16* __restrict__ pB,
    f16* __restrict__ outa, f16* __restrict__ outb,
    float* __restrict__ outf, const float* __restrict__ bias)
{
    __shared__ f16 As[128 * 32];   // 8 KB
    __shared__ f16 Bs[128 * 32];   // 8 KB
    const int t = threadIdx.x;
    const int lane = t & 63;
    const int w = t >> 6;
    const int wm = w & 1, wn = w >> 1;
    const int quad = lane >> 4, l15 = lane & 15;

    const int n0 = blockIdx.x * 128;   // col tile fastest -> A reuse in L2
    const int m0 = blockIdx.y * 128;
    int vb = 0, vp = 0, z = 0;

    const f16* Abase; size_t sA;
    const f16* Bbase; size_t sB;
    if constexpr (MODE == MODE_QK) {
        if (n0 < 512) { Abase = pA;  sA = 8192; }   // x p=0 slice
        else          { Abase = pA2; sA = 512;  }   // xmean
        Bbase = pB; sB = 512;                       // WT rows
    } else if constexpr (MODE == MODE_V) {
        z = blockIdx.z; vb = z >> 4; vp = z & 15;
        Abase = pA; sA = 512;                       // WvT rows
        Bbase = pB + ((size_t)vb * 512 * 16 + vp) * 512; sB = 8192; // x[b,:,p,:]
    } else if constexpr (MODE == MODE_PV) {
        z = blockIdx.z;                             // bh
        Abase = pA + (size_t)z * 512 * 512; sA = 512;   // P rows
        Bbase = pB + (size_t)z * 1024 * 512; sB = 512;  // vT rows
    } else {
        Abase = pA; sA = 512;                       // ypre rows
        Bbase = pB; sB = 512;                       // WpT rows
    }

    // staging: A tile = 8 chunks of 16 rows (1024 B each); wave w owns
    // chunks {w, w+4}. lane covers row-in-chunk = lane>>2, k = (lane&3)*8.
    const int rlo = (lane >> 2), kof = (lane & 3) * 8;
    const f16* ga0 = Abase + (size_t)(m0 + w * 16 + rlo) * sA + kof;
    const f16* ga1 = Abase + (size_t)(m0 + (w + 4) * 16 + rlo) * sA + kof;
    const f16* gb0 = Bbase + (size_t)(n0 + w * 16 + rlo) * sB + kof;
    const f16* gb1 = Bbase + (size_t)(n0 + (w + 4) * 16 + rlo) * sB + kof;
    f16* lA0 = As + w * 512;        // wave-uniform LDS bases
    f16* lA1 = As + (w + 4) * 512;
    f16* lB0 = Bs + w * 512;
    f16* lB1 = Bs + (w + 4) * 512;

    float4v acc[4][4];
    #pragma unroll
    for (int i = 0; i < 4; i++)
        #pragma unroll
        for (int j = 0; j < 4; j++)
            acc[i][j] = (float4v){0.f, 0.f, 0.f, 0.f};

    for (int kt = 0; kt < 16; kt++) {
        __syncthreads();           // prior reads done before overwrite
        gload16(ga0, lA0); gload16(ga1, lA1);
        gload16(gb0, lB0); gload16(gb1, lB1);
        ga0 += 32; ga1 += 32; gb0 += 32; gb1 += 32;
        __syncthreads();           // compiler drains vmcnt before barrier
        half8 af[4], bf[4];
        #pragma unroll
        for (int mi = 0; mi < 4; mi++)
            af[mi] = *(const half8*)&As[(wm * 64 + mi * 16 + l15) * 32 + quad * 8];
        #pragma unroll
        for (int ni = 0; ni < 4; ni++)
            bf[ni] = *(const half8*)&Bs[(wn * 64 + ni * 16 + l15) * 32 + quad * 8];
        #pragma unroll
        for (int mi = 0; mi < 4; mi++)
            #pragma unroll
            for (int ni = 0; ni < 4; ni++)
                acc[mi][ni] = __builtin_amdgcn_mfma_f32_16x16x32_f16(
                    af[mi], bf[ni], acc[mi][ni], 0, 0, 0);
    }

    #pragma unroll
    for (int mi = 0; mi < 4; mi++) {
        #pragma unroll
        for (int ni = 0; ni < 4; ni++) {
            #pragma unroll
            for (int i = 0; i < 4; i++) {
                int lrow = wm * 64 + mi * 16 + quad * 4 + i;
                int lcol = wn * 64 + ni * 16 + l15;
                float val = acc[mi][ni][i];
                if constexpr (MODE == MODE_QK) {
                    int gm = m0 + lrow, gj = n0 + lcol;
                    int b = gm >> 9, n = gm & 511;
                    if (gj < 512)
                        outa[(((size_t)(b * 8 + (gj >> 6))) * 512 + n) * 64 + (gj & 63)] = (f16)val;
                    else {
                        int jj = gj - 512;
                        outb[(((size_t)(b * 8 + (jj >> 6))) * 512 + n) * 64 + (jj & 63)] = (f16)val;
                    }
                } else if constexpr (MODE == MODE_V) {
                    int gi = m0 + lrow, gn = n0 + lcol;
                    int h = gi >> 6, dd = gi & 63;   // e' order: p*64+dd
                    outa[(((size_t)(vb * 8 + h)) * 1024 + vp * 64 + dd) * 512 + gn] = (f16)val;
                } else if constexpr (MODE == MODE_PV) {
                    // direct ypre store: e' = p*64+dd
                    int n = m0 + lrow, e = n0 + lcol;
                    int p = e >> 6, dd = e & 63;
                    int b = z >> 3, h = z & 7;
                    outa[((size_t)(b * 512 + n) * 16 + p) * 512 + h * 64 + dd] = (f16)val;
                } else {
                    outf[(size_t)(m0 + lrow) * 512 + (n0 + lcol)] = val + bias[n0 + lcol];
                }
            }
        }
    }
}

// Fused S = q k^T * 0.125 and row softmax, writes P (f16, normalized).
// grid (8 ntiles, 64 bh); block 256; wave w owns q-rows n0+16w..+16, all 512 cols.
__global__ __launch_bounds__(256) void qk_softmax_kernel(
    const f16* __restrict__ q, const f16* __restrict__ k, f16* __restrict__ Pout)
{
    __shared__ f16 qs[64 * 72];
    __shared__ f16 ks[512 * 72];
    const int t = threadIdx.x;
    const int bh = blockIdx.y;
    const int n0 = blockIdx.x * 64;
    #pragma unroll
    for (int i = 0; i < 2; i++) {
        int cid = i * 256 + t;
        int row = cid >> 3, off = (cid & 7) * 8;
        *(half8*)&qs[row * 72 + off] =
            *(const half8*)&q[((size_t)bh * 512 + n0 + row) * 64 + off];
    }
    #pragma unroll
    for (int i = 0; i < 16; i++) {
        int cid = i * 256 + t;
        int row = cid >> 3, off = (cid & 7) * 8;
        *(half8*)&ks[row * 72 + off] =
            *(const half8*)&k[((size_t)bh * 512 + row) * 64 + off];
    }
    __syncthreads();
    const int lane = t & 63, w = t >> 6;
    const int quad = lane >> 4, l15 = lane & 15;
    const int qrow = w * 16 + l15;
    half8 a0 = *(const half8*)&qs[qrow * 72 + quad * 8];
    half8 a1 = *(const half8*)&qs[qrow * 72 + 32 + quad * 8];
    float4v acc[32];
    #pragma unroll
    for (int f = 0; f < 32; f++) {
        int krow = f * 16 + l15;
        half8 b0 = *(const half8*)&ks[krow * 72 + quad * 8];
        half8 b1 = *(const half8*)&ks[krow * 72 + 32 + quad * 8];
        float4v c = {0.f, 0.f, 0.f, 0.f};
        c = __builtin_amdgcn_mfma_f32_16x16x32_f16(a0, b0, c, 0, 0, 0);
        c = __builtin_amdgcn_mfma_f32_16x16x32_f16(a1, b1, c, 0, 0, 0);
        acc[f] = c;
    }
    float mx0 = -3e38f, mx1 = -3e38f, mx2 = -3e38f, mx3 = -3e38f;
    #pragma unroll
    for (int f = 0; f < 32; f++) {
        mx0 = fmaxf(mx0, acc[f][0]); mx1 = fmaxf(mx1, acc[f][1]);
        mx2 = fmaxf(mx2, acc[f][2]); mx3 = fmaxf(mx3, acc[f][3]);
    }
    #pragma unroll
    for (int off = 1; off < 16; off <<= 1) {
        mx0 = fmaxf(mx0, __shfl_xor(mx0, off));
        mx1 = fmaxf(mx1, __shfl_xor(mx1, off));
        mx2 = fmaxf(mx2, __shfl_xor(mx2, off));
        mx3 = fmaxf(mx3, __shfl_xor(mx3, off));
    }
    float s0 = 0.f, s1 = 0.f, s2 = 0.f, s3 = 0.f;
    #pragma unroll
    for (int f = 0; f < 32; f++) {
        float e0 = __expf(0.125f * (acc[f][0] - mx0));
        float e1 = __expf(0.125f * (acc[f][1] - mx1));
        float e2 = __expf(0.125f * (acc[f][2] - mx2));
        float e3 = __expf(0.125f * (acc[f][3] - mx3));
        acc[f][0] = e0; acc[f][1] = e1; acc[f][2] = e2; acc[f][3] = e3;
        s0 += e0; s1 += e1; s2 += e2; s3 += e3;
    }
    #pragma unroll
    for (int off = 1; off < 16; off <<= 1) {
        s0 += __shfl_xor(s0, off);
        s1 += __shfl_xor(s1, off);
        s2 += __shfl_xor(s2, off);
        s3 += __shfl_xor(s3, off);
    }
    float r0 = 1.f / s0, r1 = 1.f / s1, r2 = 1.f / s2, r3 = 1.f / s3;
    size_t base = ((size_t)bh * 512 + n0 + w * 16) * 512;
    #pragma unroll
    for (int f = 0; f < 32; f++) {
        int col = f * 16 + l15;
        Pout[base + (size_t)(quad * 4 + 0) * 512 + col] = (f16)(acc[f][0] * r0);
        Pout[base + (size_t)(quad * 4 + 1) * 512 + col] = (f16)(acc[f][1] * r1);
        Pout[base + (size_t)(quad * 4 + 2) * 512 + col] = (f16)(acc[f][2] * r2);
        Pout[base + (size_t)(quad * 4 + 3) * 512 + col] = (f16)(acc[f][3] * r3);
    }
}

extern "C" void kernel_launch(void* const* d_in, const int* in_sizes, int n_in,
                              void* d_out, int out_size, void* d_ws, size_t ws_size,
                              hipStream_t stream)
{
    (void)in_sizes; (void)n_in; (void)out_size; (void)ws_size;
    const float* x     = (const float*)d_in[0];
    const float* mask  = (const float*)d_in[1];
    // d_in[2] lens, d_in[3] lens_mask: unused by the reference forward
    const float* Wqkv  = (const float*)d_in[4];
    const float* Wproj = (const float*)d_in[5];
    const float* bproj = (const float*)d_in[6];
    float* out = (float*)d_out;
    char* ws = (char*)d_ws;

    f16* xf16  = (f16*)(ws + 0);
    f16* vT    = (f16*)(ws + 67108864);
    f16* xmean = (f16*)(ws + 134217728);
    f16* WT    = (f16*)(ws + 138412032);
    f16* WpT   = (f16*)(ws + 139984896);
    f16* qb    = (f16*)(ws + 140509184);
    f16* kb    = (f16*)(ws + 144703488);
    f16* Pm    = (f16*)(ws + 148897792);
    f16* ypre  = xf16;   // xf16 dead after V GEMM; PV writes here, PROJ reads

    wt_kernel<<<dim3(4096), dim3(256), 0, stream>>>(Wqkv, Wproj, WT, WpT);
    xprep_kernel<<<dim3(4096), dim3(256), 0, stream>>>(x, mask, xf16, xmean);
    gemm128<MODE_QK><<<dim3(8, 32), dim3(256), 0, stream>>>(
        xf16, xmean, WT, qb, kb, nullptr, nullptr);
    gemm128<MODE_V><<<dim3(4, 4, 128), dim3(256), 0, stream>>>(
        WT + 1024 * 512, nullptr, xf16, vT, nullptr, nullptr, nullptr);
    qk_softmax_kernel<<<dim3(8, 64), dim3(256), 0, stream>>>(qb, kb, Pm);
    gemm128<MODE_PV><<<dim3(8, 4, 64), dim3(256), 0, stream>>>(
        Pm, nullptr, vT, ypre, nullptr, nullptr, nullptr);
    gemm128<MODE_PROJ><<<dim3(4, 512), dim3(256), 0, stream>>>(
        ypre, nullptr, WpT, nullptr, nullptr, out, bproj);
}